// Round 2
// baseline (1099.068 us; speedup 1.0000x reference)
//
#include <hip/hip_runtime.h>
#include <hip/hip_bf16.h>

#define F_IN   1024
#define H_DIM  128
#define D_VQE  64
#define K_CODES 512

// ---------------- fp32 GEMM, N=64 (xq projection only): C = A[M,K] @ W[K,64] + b ----------------
constexpr int BM = 64, BN = 64, BK = 16;

__global__ __launch_bounds__(256) void gemm_n64(
    const float* __restrict__ A, int lda,
    const float* __restrict__ W, int ldw,
    const float* __restrict__ bias,
    float* __restrict__ C, int ldc, int K)
{
    __shared__ float As[BK][BM + 4];
    __shared__ float Bs[BK][BN];
    const int t  = threadIdx.x;
    const int tx = t & 15, ty = t >> 4;
    const int row0 = blockIdx.x * BM;

    const int arow = t >> 2;
    const int ak   = (t & 3) << 2;
    const int bk   = t >> 4;
    const int bc   = (t & 15) << 2;

    const float* Ap = A + (size_t)(row0 + arow) * lda + ak;
    const float* Wp = W + (size_t)bk * ldw + bc;

    float acc[4][4] = {};
    for (int k0 = 0; k0 < K; k0 += BK) {
        float4 a4 = *(const float4*)(Ap + k0);
        float4 b4 = *(const float4*)(Wp + (size_t)k0 * ldw);
        As[ak + 0][arow] = a4.x;
        As[ak + 1][arow] = a4.y;
        As[ak + 2][arow] = a4.z;
        As[ak + 3][arow] = a4.w;
        *(float4*)&Bs[bk][bc] = b4;
        __syncthreads();
#pragma unroll
        for (int k = 0; k < BK; ++k) {
            float4 av = *(const float4*)&As[k][ty << 2];
            float4 bv = *(const float4*)&Bs[k][tx << 2];
            acc[0][0] += av.x * bv.x; acc[0][1] += av.x * bv.y; acc[0][2] += av.x * bv.z; acc[0][3] += av.x * bv.w;
            acc[1][0] += av.y * bv.x; acc[1][1] += av.y * bv.y; acc[1][2] += av.y * bv.z; acc[1][3] += av.y * bv.w;
            acc[2][0] += av.z * bv.x; acc[2][1] += av.z * bv.y; acc[2][2] += av.z * bv.z; acc[2][3] += av.z * bv.w;
            acc[3][0] += av.w * bv.x; acc[3][1] += av.w * bv.y; acc[3][2] += av.w * bv.z; acc[3][3] += av.w * bv.w;
        }
        __syncthreads();
    }

    float4 b4 = *(const float4*)(bias + (tx << 2));
#pragma unroll
    for (int i = 0; i < 4; ++i) {
        float4 o;
        o.x = acc[i][0] + b4.x; o.y = acc[i][1] + b4.y;
        o.z = acc[i][2] + b4.z; o.w = acc[i][3] + b4.w;
        *(float4*)(C + (size_t)(row0 + (ty << 2) + i) * ldc + (tx << 2)) = o;
    }
}

// ---------------- fused fp32 GEMM, N=128: MODE 0 relu->fp32, 1 softmax->fp32 probs, 2 relu+dot(w2)->fp32 critic ----------------
template<int MODE>
__global__ __launch_bounds__(256) void gemm128(
    const float* __restrict__ A, int lda, int K,
    const float* __restrict__ W,        // [K,128]
    const float* __restrict__ bias,     // [128]
    const float* __restrict__ w2,       // [128]  (MODE 2 only)
    const float* __restrict__ b2,       // [1]    (MODE 2 only)
    float* __restrict__ out)            // MODE 0/1: [M,128]; MODE 2: [M]
{
    __shared__ float As[16][68];        // A^T tile, 64 rows, +4 pad
    __shared__ float Bs[16][128];
    __shared__ float w2s[128];
    const int t  = threadIdx.x;
    const int tx = t & 15, ty = t >> 4; // thread = 4 rows x 8 cols
    const int row0 = blockIdx.x * 64;

    if (MODE == 2 && t < 32) *(float4*)&w2s[t << 2] = *(const float4*)&w2[t << 2];

    const int arow = t >> 2;
    const int ak   = (t & 3) << 2;
    const int bk   = t >> 4;
    const int bc   = (t & 15) << 3;
    const float* Ap = A + (size_t)(row0 + arow) * lda + ak;
    const float* Wp = W + (size_t)bk * 128 + bc;

    float acc[4][8] = {};
    for (int k0 = 0; k0 < K; k0 += 16) {
        float4 a4 = *(const float4*)(Ap + k0);
        float4 w0 = *(const float4*)(Wp + (size_t)k0 * 128);
        float4 w1 = *(const float4*)(Wp + (size_t)k0 * 128 + 4);
        As[ak + 0][arow] = a4.x;
        As[ak + 1][arow] = a4.y;
        As[ak + 2][arow] = a4.z;
        As[ak + 3][arow] = a4.w;
        *(float4*)&Bs[bk][bc]     = w0;
        *(float4*)&Bs[bk][bc + 4] = w1;
        __syncthreads();
#pragma unroll
        for (int k = 0; k < 16; ++k) {
            float4 av = *(const float4*)&As[k][ty << 2];
            float4 b0 = *(const float4*)&Bs[k][tx << 3];
            float4 b1 = *(const float4*)&Bs[k][(tx << 3) + 4];
            float am[4] = {av.x, av.y, av.z, av.w};
#pragma unroll
            for (int i = 0; i < 4; ++i) {
                acc[i][0] += am[i] * b0.x; acc[i][1] += am[i] * b0.y;
                acc[i][2] += am[i] * b0.z; acc[i][3] += am[i] * b0.w;
                acc[i][4] += am[i] * b1.x; acc[i][5] += am[i] * b1.y;
                acc[i][6] += am[i] * b1.z; acc[i][7] += am[i] * b1.w;
            }
        }
        __syncthreads();
    }

    float4 bb0 = *(const float4*)&bias[tx << 3];
    float4 bb1 = *(const float4*)&bias[(tx << 3) + 4];
    float bcol[8] = {bb0.x, bb0.y, bb0.z, bb0.w, bb1.x, bb1.y, bb1.z, bb1.w};

#pragma unroll
    for (int i = 0; i < 4; ++i) {
        const size_t r = (size_t)row0 + (ty << 2) + i;
        float v[8];
#pragma unroll
        for (int j = 0; j < 8; ++j) v[j] = acc[i][j] + bcol[j];
        if (MODE == 0) {
#pragma unroll
            for (int j = 0; j < 8; ++j) v[j] = fmaxf(v[j], 0.f);
            float4 o0 = {v[0], v[1], v[2], v[3]};
            float4 o1 = {v[4], v[5], v[6], v[7]};
            *(float4*)(out + r * 128 + (tx << 3))     = o0;
            *(float4*)(out + r * 128 + (tx << 3) + 4) = o1;
        } else if (MODE == 1) {
            // row softmax across the 16 lanes sharing this row (xor on tx bits stays in-group)
            float m = v[0];
#pragma unroll
            for (int j = 1; j < 8; ++j) m = fmaxf(m, v[j]);
            for (int off = 1; off < 16; off <<= 1) m = fmaxf(m, __shfl_xor(m, off, 64));
            float s = 0.f;
#pragma unroll
            for (int j = 0; j < 8; ++j) { v[j] = __expf(v[j] - m); s += v[j]; }
            for (int off = 1; off < 16; off <<= 1) s += __shfl_xor(s, off, 64);
            float inv = 1.0f / s;
            float4 o0 = {v[0] * inv, v[1] * inv, v[2] * inv, v[3] * inv};
            float4 o1 = {v[4] * inv, v[5] * inv, v[6] * inv, v[7] * inv};
            *(float4*)(out + r * 128 + (tx << 3))     = o0;
            *(float4*)(out + r * 128 + (tx << 3) + 4) = o1;
        } else {
            float p = 0.f;
#pragma unroll
            for (int j = 0; j < 8; ++j) { float rv = fmaxf(v[j], 0.f); p += rv * w2s[(tx << 3) + j]; }
            for (int off = 1; off < 16; off <<= 1) p += __shfl_xor(p, off, 64);
            if (tx == 0) out[r] = p + b2[0];
        }
    }
}

// ---------------- VQ: argmin_j (sx - 2*dot + ||E_j||^2), fp32, first-min tiebreak ----------------
__global__ __launch_bounds__(256) void vq_kernel(
    const float* __restrict__ xq, const float* __restrict__ E,
    float* __restrict__ idx_out, float* __restrict__ accum)
{
    __shared__ float Es[128 * D_VQE];
    __shared__ float en[128];
    __shared__ float wsum[4];

    const int t = threadIdx.x;
    const size_t row = (size_t)blockIdx.x * 256 + t;

    float x[D_VQE];
    const float* xr = xq + row * D_VQE;
#pragma unroll
    for (int d = 0; d < D_VQE; d += 4) {
        float4 v = *(const float4*)(xr + d);
        x[d] = v.x; x[d + 1] = v.y; x[d + 2] = v.z; x[d + 3] = v.w;
    }
    float sx = 0.f;
#pragma unroll
    for (int d = 0; d < D_VQE; ++d) sx += x[d] * x[d];

    float best = 3.4e38f;
    int bj = 0;

    for (int q = 0; q < 4; ++q) {
        __syncthreads();
        const float4* src = (const float4*)(E + (size_t)q * 128 * D_VQE);
        float4* dst = (float4*)Es;
        for (int i = t; i < 128 * D_VQE / 4; i += 256) dst[i] = src[i];
        __syncthreads();
        if (t < 128) {
            float s = 0.f;
            const float* e = &Es[t * D_VQE];
#pragma unroll 8
            for (int d = 0; d < D_VQE; ++d) s += e[d] * e[d];
            en[t] = s;
        }
        __syncthreads();
        for (int j = 0; j < 128; ++j) {
            const float* e = &Es[j * D_VQE];
            float d0 = 0.f, d1 = 0.f, d2 = 0.f, d3 = 0.f;
#pragma unroll
            for (int d = 0; d < D_VQE; d += 4) {
                float4 ev = *(const float4*)(e + d);
                d0 += x[d]     * ev.x;
                d1 += x[d + 1] * ev.y;
                d2 += x[d + 2] * ev.z;
                d3 += x[d + 3] * ev.w;
            }
            float dot = (d0 + d1) + (d2 + d3);
            float dist = sx - 2.0f * dot + en[j];
            if (dist < best) { best = dist; bj = q * 128 + j; }
        }
    }

    idx_out[row] = (float)bj;

    float err = 0.f;
    const float* eb = E + (size_t)bj * D_VQE;
#pragma unroll
    for (int d = 0; d < D_VQE; d += 4) {
        float4 ev = *(const float4*)(eb + d);
        float e0 = ev.x - x[d], e1 = ev.y - x[d + 1], e2 = ev.z - x[d + 2], e3 = ev.w - x[d + 3];
        err += e0 * e0 + e1 * e1 + e2 * e2 + e3 * e3;
    }
    for (int off = 32; off > 0; off >>= 1) err += __shfl_down(err, off, 64);
    if ((t & 63) == 0) wsum[t >> 6] = err;
    __syncthreads();
    if (t == 0) atomicAdd(accum, wsum[0] + wsum[1] + wsum[2] + wsum[3]);
}

__global__ void vq_fin(const float* __restrict__ accum, float* __restrict__ out, float scale)
{
    out[0] = accum[0] * scale;
}

extern "C" void kernel_launch(void* const* d_in, const int* in_sizes, int n_in,
                              void* d_out, int out_size, void* d_ws, size_t ws_size,
                              hipStream_t stream)
{
    const float* x    = (const float*)d_in[0];
    const float* W_e0 = (const float*)d_in[1];
    const float* b_e0 = (const float*)d_in[2];
    const float* W_e1 = (const float*)d_in[3];
    const float* b_e1 = (const float*)d_in[4];
    const float* W_e2 = (const float*)d_in[5];
    const float* b_e2 = (const float*)d_in[6];
    const float* W_p  = (const float*)d_in[7];
    const float* b_p  = (const float*)d_in[8];
    const float* E    = (const float*)d_in[9];
    const float* W_a0 = (const float*)d_in[10];
    const float* b_a0 = (const float*)d_in[11];
    const float* W_a1 = (const float*)d_in[12];
    const float* b_a1 = (const float*)d_in[13];
    const float* W_c0 = (const float*)d_in[14];
    const float* b_c0 = (const float*)d_in[15];
    const float* W_c1 = (const float*)d_in[16];
    const float* b_c1 = (const float*)d_in[17];
    const float* W_c2 = (const float*)d_in[18];
    const float* b_c2 = (const float*)d_in[19];

    const size_t B = (size_t)in_sizes[0] / F_IN;   // 65536

    // workspace: exactly 2 fp32 ping-pong buffers of B x 128 (67.1 MB).
    // xq (B x 64 fp32) lives in buf1's lower half until vq completes; accum just past it.
    float* buf0  = (float*)d_ws;
    float* buf1  = buf0 + B * H_DIM;
    float* xq    = buf1;
    float* accum = buf1 + B * D_VQE;

    // d_out is FLOAT32 (reference outputs are fp32/int32, not bf16)
    float* out   = (float*)d_out;
    float* probs = out;                       // B*128
    float* crit  = out + B * H_DIM;           // B
    float* loss  = crit + B;                  // 1
    float* idxo  = loss + 1;                  // B

    hipMemsetAsync(accum, 0, sizeof(float), stream);

    dim3 blk(256);
    const int nb = (int)(B / 64);

    // xq = x @ W_p + b_p (fp32, precision-critical for argmin)
    gemm_n64<<<dim3(nb), blk, 0, stream>>>(x, F_IN, W_p, D_VQE, b_p, xq, D_VQE, F_IN);
    vq_kernel<<<dim3((int)(B / 256)), blk, 0, stream>>>(xq, E, idxo, accum);
    vq_fin<<<1, 1, 0, stream>>>(accum, loss, 1.25f / ((float)B * (float)D_VQE));

    // embedding tower (xq/accum in buf1 are dead after vq_fin)
    gemm128<0><<<dim3(nb), blk, 0, stream>>>(x,    F_IN,  F_IN,  W_e0, b_e0, nullptr, nullptr, buf0);
    gemm128<0><<<dim3(nb), blk, 0, stream>>>(buf0, H_DIM, H_DIM, W_e1, b_e1, nullptr, nullptr, buf1);
    gemm128<0><<<dim3(nb), blk, 0, stream>>>(buf1, H_DIM, H_DIM, W_e2, b_e2, nullptr, nullptr, buf0);
    // actor: a0 then fused a1+softmax -> probs (fp32)
    gemm128<0><<<dim3(nb), blk, 0, stream>>>(buf0, H_DIM, H_DIM, W_a0, b_a0, nullptr, nullptr, buf1);
    gemm128<1><<<dim3(nb), blk, 0, stream>>>(buf1, H_DIM, H_DIM, W_a1, b_a1, nullptr, nullptr, probs);
    // critic: c0 then fused c1+relu+dot(W_c2) -> critic (fp32)
    gemm128<0><<<dim3(nb), blk, 0, stream>>>(buf0, H_DIM, H_DIM, W_c0, b_c0, nullptr, nullptr, buf1);
    gemm128<2><<<dim3(nb), blk, 0, stream>>>(buf1, H_DIM, H_DIM, W_c1, b_c1, W_c2, b_c2, crit);
}

// Round 3
// 782.306 us; speedup vs baseline: 1.4049x; 1.4049x over previous
//
#include <hip/hip_runtime.h>
#include <hip/hip_bf16.h>

#define F_IN   1024
#define H_DIM  128
#define D_VQE  64
#define K_CODES 512

typedef __attribute__((ext_vector_type(8))) short s8v;   // 8 bf16 = one MFMA A/B frag
typedef __attribute__((ext_vector_type(4))) float f4v;   // MFMA C/D frag

static __device__ __forceinline__ unsigned f2bf(float f) {
    unsigned u = __builtin_bit_cast(unsigned, f);
    return (u + 0x7fffu + ((u >> 16) & 1u)) >> 16;   // RNE, no NaN inputs here
}

static __device__ __forceinline__ f4v mfma16x16x32(s8v a, s8v b, f4v c) {
    return __builtin_amdgcn_mfma_f32_16x16x32_bf16(a, b, c, 0, 0, 0);
}

// ---------------- weight prep: 7 tower weights fp32 [K,N] -> bf16 W^T [N][K] ----------------
__global__ __launch_bounds__(256) void conv_weights(
    const float* __restrict__ W0,  // [1024,128]
    const float* __restrict__ W1, const float* __restrict__ W2,
    const float* __restrict__ W3, const float* __restrict__ W4,
    const float* __restrict__ W5, const float* __restrict__ W6,  // each [128,128]
    short* __restrict__ out)
{
    int g = blockIdx.x * 256 + threadIdx.x;
    if (g < 131072) {
        int n = g >> 10, k = g & 1023;
        out[g] = (short)f2bf(W0[k * 128 + n]);
    } else {
        int r = g - 131072;
        int which = r >> 14, o = r & 16383;
        int n = o >> 7, k = o & 127;
        const float* Ws[6] = {W1, W2, W3, W4, W5, W6};
        out[131072 + which * 16384 + n * 128 + k] = (short)f2bf(Ws[which][k * 128 + n]);
    }
}

// ---------------- e0: [B,1024] fp32 -> relu(x@W_e0+b) -> bf16 [B,128], MFMA ----------------
// 128x128 tile, K chunks of 64 (fp32 x converted to bf16 during LDS staging).
__global__ __launch_bounds__(256) void gemm_e0(
    const float* __restrict__ A,     // [B,1024] fp32
    const short* __restrict__ Wt,    // [128][1024] bf16 (n-major)
    const float* __restrict__ bias,  // [128] fp32
    short* __restrict__ out)         // [B,128] bf16
{
    __shared__ __align__(16) char smem[36864];
    short* As = (short*)smem;            // [128][72] bf16 chunk (k width 64)
    short* Bs = (short*)(smem + 18432);  // [128][72] bf16 chunk
    short* Cs = (short*)smem;            // [128][136] epilogue staging (overlaps)

    const int t = threadIdx.x;
    const int lane = t & 63, w = t >> 6;
    const int l15 = lane & 15, q = lane >> 4;
    const size_t row0 = (size_t)blockIdx.x * 128;

    f4v acc[2][8];
#pragma unroll
    for (int i = 0; i < 2; ++i)
#pragma unroll
        for (int j = 0; j < 8; ++j) acc[i][j] = {0.f, 0.f, 0.f, 0.f};

    for (int ch = 0; ch < 16; ++ch) {   // k0 = ch*64
        __syncthreads();
        // stage A chunk: 128 rows x 64 fp32 -> bf16; 16 float4/row, 8 per thread
#pragma unroll
        for (int i = 0; i < 8; ++i) {
            int c = t + 256 * i;
            int r = c >> 4, c4 = c & 15;
            float4 a4 = *(const float4*)(A + (row0 + r) * 1024 + ch * 64 + c4 * 4);
            unsigned p01 = f2bf(a4.x) | (f2bf(a4.y) << 16);
            unsigned p23 = f2bf(a4.z) | (f2bf(a4.w) << 16);
            *(int2*)(As + r * 72 + c4 * 4) = make_int2((int)p01, (int)p23);
        }
        // stage W^T chunk: 128 rows x 64 bf16 = 128B/row = 8x16B, 4 per thread
#pragma unroll
        for (int i = 0; i < 4; ++i) {
            int c = t + 256 * i;
            int n = c >> 3, c16 = c & 7;
            *(int4*)(Bs + n * 72 + c16 * 8) = *(const int4*)(Wt + (size_t)n * 1024 + ch * 64 + c16 * 8);
        }
        __syncthreads();
#pragma unroll
        for (int kc = 0; kc < 2; ++kc) {
            int kb = kc * 32 + q * 8;
            s8v a0 = *(const s8v*)(As + (w * 32 + l15) * 72 + kb);
            s8v a1 = *(const s8v*)(As + (w * 32 + 16 + l15) * 72 + kb);
#pragma unroll
            for (int ct = 0; ct < 8; ++ct) {
                s8v b = *(const s8v*)(Bs + (ct * 16 + l15) * 72 + kb);
                acc[0][ct] = mfma16x16x32(a0, b, acc[0][ct]);
                acc[1][ct] = mfma16x16x32(a1, b, acc[1][ct]);
            }
        }
    }

    float bias_v[8];
#pragma unroll
    for (int ct = 0; ct < 8; ++ct) bias_v[ct] = bias[ct * 16 + l15];

    __syncthreads();
#pragma unroll
    for (int rt = 0; rt < 2; ++rt)
#pragma unroll
        for (int ct = 0; ct < 8; ++ct)
#pragma unroll
            for (int reg = 0; reg < 4; ++reg) {
                float v = acc[rt][ct][reg] + bias_v[ct];
                v = fmaxf(v, 0.f);
                Cs[(w * 32 + rt * 16 + q * 4 + reg) * 136 + ct * 16 + l15] = (short)f2bf(v);
            }
    __syncthreads();
#pragma unroll
    for (int i = 0; i < 8; ++i) {
        int c = t + 256 * i;
        int r = c >> 4, c16 = c & 15;
        *(int4*)(out + (row0 + r) * 128 + c16 * 8) = *(const int4*)(Cs + r * 136 + c16 * 8);
    }
}

// ---------------- tower GEMM: bf16 [B,128] @ W[128,128], MFMA, fused epilogues ----------------
// MODE 0: relu -> bf16 [B,128];  1: softmax -> fp32 [B,128];  2: relu+dot(w2)+b2 -> fp32 [B]
template<int MODE>
__global__ __launch_bounds__(256) void gemm_h(
    const short* __restrict__ A,     // [B,128] bf16
    const short* __restrict__ Wt,    // [128][128] bf16 (n-major)
    const float* __restrict__ bias,  // [128] fp32
    const float* __restrict__ w2,    // [128] fp32 (MODE 2)
    const float* __restrict__ b2,    // [1]   fp32 (MODE 2)
    void* __restrict__ outv)
{
    __shared__ __align__(16) char smem[53248];
    short* As = (short*)smem;            // [128][72] bf16 chunk (k width 64)
    short* Bs = (short*)(smem + 18432);  // [128][136] bf16 full weights
    short* Cs = (short*)smem;            // [128][136] epilogue staging (MODE 0)

    const int t = threadIdx.x;
    const int lane = t & 63, w = t >> 6;
    const int l15 = lane & 15, q = lane >> 4;
    const size_t row0 = (size_t)blockIdx.x * 128;

    // stage full W^T: 128 rows x 256B = 2048x16B chunks? -> 16 chunks/row, 8 per thread
#pragma unroll
    for (int i = 0; i < 8; ++i) {
        int c = t + 256 * i;
        int n = c >> 4, c16 = c & 15;
        *(int4*)(Bs + n * 136 + c16 * 8) = *(const int4*)(Wt + n * 128 + c16 * 8);
    }

    f4v acc[2][8];
#pragma unroll
    for (int i = 0; i < 2; ++i)
#pragma unroll
        for (int j = 0; j < 8; ++j) acc[i][j] = {0.f, 0.f, 0.f, 0.f};

#pragma unroll
    for (int half = 0; half < 2; ++half) {
        __syncthreads();   // first iter: also covers Bs staging
        // stage A chunk: 128 rows x 64 bf16 = 128B/row = 8x16B, 4 per thread
#pragma unroll
        for (int i = 0; i < 4; ++i) {
            int c = t + 256 * i;
            int r = c >> 3, c16 = c & 7;
            *(int4*)(As + r * 72 + c16 * 8) = *(const int4*)(A + (row0 + r) * 128 + half * 64 + c16 * 8);
        }
        __syncthreads();
#pragma unroll
        for (int kc = 0; kc < 2; ++kc) {
            int kb = kc * 32 + q * 8;
            int kg = half * 64 + kb;
            s8v a0 = *(const s8v*)(As + (w * 32 + l15) * 72 + kb);
            s8v a1 = *(const s8v*)(As + (w * 32 + 16 + l15) * 72 + kb);
#pragma unroll
            for (int ct = 0; ct < 8; ++ct) {
                s8v b = *(const s8v*)(Bs + (ct * 16 + l15) * 136 + kg);
                acc[0][ct] = mfma16x16x32(a0, b, acc[0][ct]);
                acc[1][ct] = mfma16x16x32(a1, b, acc[1][ct]);
            }
        }
    }

    float bias_v[8];
#pragma unroll
    for (int ct = 0; ct < 8; ++ct) bias_v[ct] = bias[ct * 16 + l15];

    if (MODE == 0) {
        short* out = (short*)outv;
        __syncthreads();
#pragma unroll
        for (int rt = 0; rt < 2; ++rt)
#pragma unroll
            for (int ct = 0; ct < 8; ++ct)
#pragma unroll
                for (int reg = 0; reg < 4; ++reg) {
                    float v = acc[rt][ct][reg] + bias_v[ct];
                    v = fmaxf(v, 0.f);
                    Cs[(w * 32 + rt * 16 + q * 4 + reg) * 136 + ct * 16 + l15] = (short)f2bf(v);
                }
        __syncthreads();
#pragma unroll
        for (int i = 0; i < 8; ++i) {
            int c = t + 256 * i;
            int r = c >> 4, c16 = c & 15;
            *(int4*)(out + (row0 + r) * 128 + c16 * 8) = *(const int4*)(Cs + r * 136 + c16 * 8);
        }
    } else if (MODE == 1) {
        float* out = (float*)outv;
#pragma unroll
        for (int rt = 0; rt < 2; ++rt)
#pragma unroll
            for (int reg = 0; reg < 4; ++reg) {
                size_t m = row0 + w * 32 + rt * 16 + q * 4 + reg;
                float v[8];
                float mx = -3.4e38f;
#pragma unroll
                for (int ct = 0; ct < 8; ++ct) { v[ct] = acc[rt][ct][reg] + bias_v[ct]; mx = fmaxf(mx, v[ct]); }
#pragma unroll
                for (int off = 1; off < 16; off <<= 1) mx = fmaxf(mx, __shfl_xor(mx, off, 64));
                float s = 0.f;
#pragma unroll
                for (int ct = 0; ct < 8; ++ct) { v[ct] = __expf(v[ct] - mx); s += v[ct]; }
#pragma unroll
                for (int off = 1; off < 16; off <<= 1) s += __shfl_xor(s, off, 64);
                float inv = 1.0f / s;
#pragma unroll
                for (int ct = 0; ct < 8; ++ct) out[m * 128 + ct * 16 + l15] = v[ct] * inv;
            }
    } else {
        float* out = (float*)outv;
        float w2v[8];
#pragma unroll
        for (int ct = 0; ct < 8; ++ct) w2v[ct] = w2[ct * 16 + l15];
        float b2s = b2[0];
#pragma unroll
        for (int rt = 0; rt < 2; ++rt)
#pragma unroll
            for (int reg = 0; reg < 4; ++reg) {
                size_t m = row0 + w * 32 + rt * 16 + q * 4 + reg;
                float p = 0.f;
#pragma unroll
                for (int ct = 0; ct < 8; ++ct) p += fmaxf(acc[rt][ct][reg] + bias_v[ct], 0.f) * w2v[ct];
#pragma unroll
                for (int off = 1; off < 16; off <<= 1) p += __shfl_xor(p, off, 64);
                if (l15 == 0) out[m] = p + b2s;
            }
    }
}

// ---------------- fp32 GEMM, N=64 (xq projection — precision-critical, unchanged) ----------------
constexpr int BM = 64, BN = 64, BK = 16;

__global__ __launch_bounds__(256) void gemm_n64(
    const float* __restrict__ A, int lda,
    const float* __restrict__ W, int ldw,
    const float* __restrict__ bias,
    float* __restrict__ C, int ldc, int K)
{
    __shared__ float As[BK][BM + 4];
    __shared__ float Bs[BK][BN];
    const int t  = threadIdx.x;
    const int tx = t & 15, ty = t >> 4;
    const int row0 = blockIdx.x * BM;

    const int arow = t >> 2;
    const int ak   = (t & 3) << 2;
    const int bk   = t >> 4;
    const int bc   = (t & 15) << 2;

    const float* Ap = A + (size_t)(row0 + arow) * lda + ak;
    const float* Wp = W + (size_t)bk * ldw + bc;

    float acc[4][4] = {};
    for (int k0 = 0; k0 < K; k0 += BK) {
        float4 a4 = *(const float4*)(Ap + k0);
        float4 b4 = *(const float4*)(Wp + (size_t)k0 * ldw);
        As[ak + 0][arow] = a4.x;
        As[ak + 1][arow] = a4.y;
        As[ak + 2][arow] = a4.z;
        As[ak + 3][arow] = a4.w;
        *(float4*)&Bs[bk][bc] = b4;
        __syncthreads();
#pragma unroll
        for (int k = 0; k < BK; ++k) {
            float4 av = *(const float4*)&As[k][ty << 2];
            float4 bv = *(const float4*)&Bs[k][tx << 2];
            acc[0][0] += av.x * bv.x; acc[0][1] += av.x * bv.y; acc[0][2] += av.x * bv.z; acc[0][3] += av.x * bv.w;
            acc[1][0] += av.y * bv.x; acc[1][1] += av.y * bv.y; acc[1][2] += av.y * bv.z; acc[1][3] += av.y * bv.w;
            acc[2][0] += av.z * bv.x; acc[2][1] += av.z * bv.y; acc[2][2] += av.z * bv.z; acc[2][3] += av.z * bv.w;
            acc[3][0] += av.w * bv.x; acc[3][1] += av.w * bv.y; acc[3][2] += av.w * bv.z; acc[3][3] += av.w * bv.w;
        }
        __syncthreads();
    }

    float4 b4 = *(const float4*)(bias + (tx << 2));
#pragma unroll
    for (int i = 0; i < 4; ++i) {
        float4 o;
        o.x = acc[i][0] + b4.x; o.y = acc[i][1] + b4.y;
        o.z = acc[i][2] + b4.z; o.w = acc[i][3] + b4.w;
        *(float4*)(C + (size_t)(row0 + (ty << 2) + i) * ldc + (tx << 2)) = o;
    }
}

// ---------------- VQ: argmin_j (sx - 2*dot + ||E_j||^2), fp32, first-min tiebreak (unchanged) ----------------
__global__ __launch_bounds__(256) void vq_kernel(
    const float* __restrict__ xq, const float* __restrict__ E,
    float* __restrict__ idx_out, float* __restrict__ accum)
{
    __shared__ float Es[128 * D_VQE];
    __shared__ float en[128];
    __shared__ float wsum[4];

    const int t = threadIdx.x;
    const size_t row = (size_t)blockIdx.x * 256 + t;

    float x[D_VQE];
    const float* xr = xq + row * D_VQE;
#pragma unroll
    for (int d = 0; d < D_VQE; d += 4) {
        float4 v = *(const float4*)(xr + d);
        x[d] = v.x; x[d + 1] = v.y; x[d + 2] = v.z; x[d + 3] = v.w;
    }
    float sx = 0.f;
#pragma unroll
    for (int d = 0; d < D_VQE; ++d) sx += x[d] * x[d];

    float best = 3.4e38f;
    int bj = 0;

    for (int q = 0; q < 4; ++q) {
        __syncthreads();
        const float4* src = (const float4*)(E + (size_t)q * 128 * D_VQE);
        float4* dst = (float4*)Es;
        for (int i = t; i < 128 * D_VQE / 4; i += 256) dst[i] = src[i];
        __syncthreads();
        if (t < 128) {
            float s = 0.f;
            const float* e = &Es[t * D_VQE];
#pragma unroll 8
            for (int d = 0; d < D_VQE; ++d) s += e[d] * e[d];
            en[t] = s;
        }
        __syncthreads();
        for (int j = 0; j < 128; ++j) {
            const float* e = &Es[j * D_VQE];
            float d0 = 0.f, d1 = 0.f, d2 = 0.f, d3 = 0.f;
#pragma unroll
            for (int d = 0; d < D_VQE; d += 4) {
                float4 ev = *(const float4*)(e + d);
                d0 += x[d]     * ev.x;
                d1 += x[d + 1] * ev.y;
                d2 += x[d + 2] * ev.z;
                d3 += x[d + 3] * ev.w;
            }
            float dot = (d0 + d1) + (d2 + d3);
            float dist = sx - 2.0f * dot + en[j];
            if (dist < best) { best = dist; bj = q * 128 + j; }
        }
    }

    idx_out[row] = (float)bj;

    float err = 0.f;
    const float* eb = E + (size_t)bj * D_VQE;
#pragma unroll
    for (int d = 0; d < D_VQE; d += 4) {
        float4 ev = *(const float4*)(eb + d);
        float e0 = ev.x - x[d], e1 = ev.y - x[d + 1], e2 = ev.z - x[d + 2], e3 = ev.w - x[d + 3];
        err += e0 * e0 + e1 * e1 + e2 * e2 + e3 * e3;
    }
    for (int off = 32; off > 0; off >>= 1) err += __shfl_down(err, off, 64);
    if ((t & 63) == 0) wsum[t >> 6] = err;
    __syncthreads();
    if (t == 0) atomicAdd(accum, wsum[0] + wsum[1] + wsum[2] + wsum[3]);
}

__global__ void vq_fin(const float* __restrict__ accum, float* __restrict__ out, float scale)
{
    out[0] = accum[0] * scale;
}

extern "C" void kernel_launch(void* const* d_in, const int* in_sizes, int n_in,
                              void* d_out, int out_size, void* d_ws, size_t ws_size,
                              hipStream_t stream)
{
    const float* x    = (const float*)d_in[0];
    const float* W_e0 = (const float*)d_in[1];
    const float* b_e0 = (const float*)d_in[2];
    const float* W_e1 = (const float*)d_in[3];
    const float* b_e1 = (const float*)d_in[4];
    const float* W_e2 = (const float*)d_in[5];
    const float* b_e2 = (const float*)d_in[6];
    const float* W_p  = (const float*)d_in[7];
    const float* b_p  = (const float*)d_in[8];
    const float* E    = (const float*)d_in[9];
    const float* W_a0 = (const float*)d_in[10];
    const float* b_a0 = (const float*)d_in[11];
    const float* W_a1 = (const float*)d_in[12];
    const float* b_a1 = (const float*)d_in[13];
    const float* W_c0 = (const float*)d_in[14];
    const float* b_c0 = (const float*)d_in[15];
    const float* W_c1 = (const float*)d_in[16];
    const float* b_c1 = (const float*)d_in[17];
    const float* W_c2 = (const float*)d_in[18];
    const float* b_c2 = (const float*)d_in[19];

    const size_t B = (size_t)in_sizes[0] / F_IN;   // 65536

    // ws layout: buf0 bf16 | buf1 bf16 | wt bf16 (7 transposed weights) | xq fp32 | accum
    short* buf0 = (short*)d_ws;                       // B*128 bf16
    short* buf1 = buf0 + B * H_DIM;                   // B*128 bf16
    short* wt   = buf1 + B * H_DIM;                   // 229376 bf16 (16B-aligned)
    short* wt_e0 = wt;                                // [128][1024]
    short* wt_e1 = wt + 131072;                       // [128][128] each
    short* wt_e2 = wt_e1 + 16384;
    short* wt_a0 = wt_e2 + 16384;
    short* wt_a1 = wt_a0 + 16384;
    short* wt_c0 = wt_a1 + 16384;
    short* wt_c1 = wt_c0 + 16384;
    float* xq    = (float*)(wt + 229376);             // B*64 fp32
    float* accum = xq + B * D_VQE;

    // d_out is fp32: probs [B,128] | critic [B] | vq_loss [1] | idx [B]
    float* out   = (float*)d_out;
    float* probs = out;
    float* crit  = out + B * H_DIM;
    float* loss  = crit + B;
    float* idxo  = loss + 1;

    hipMemsetAsync(accum, 0, sizeof(float), stream);

    dim3 blk(256);
    const int nb64  = (int)(B / 64);
    const int nb128 = (int)(B / 128);

    // weight prep (bf16 transpose), 229376 elems
    conv_weights<<<dim3(896), blk, 0, stream>>>(W_e0, W_e1, W_e2, W_a0, W_a1, W_c0, W_c1, wt);

    // VQ path: fp32 end-to-end (idx must match np fp32 argmin exactly)
    gemm_n64<<<dim3(nb64), blk, 0, stream>>>(x, F_IN, W_p, D_VQE, b_p, xq, D_VQE, F_IN);
    vq_kernel<<<dim3((int)(B / 256)), blk, 0, stream>>>(xq, E, idxo, accum);
    vq_fin<<<1, 1, 0, stream>>>(accum, loss, 1.25f / ((float)B * (float)D_VQE));

    // tower: bf16 MFMA
    gemm_e0<<<dim3(nb128), blk, 0, stream>>>(x, wt_e0, b_e0, buf0);
    gemm_h<0><<<dim3(nb128), blk, 0, stream>>>(buf0, wt_e1, b_e1, nullptr, nullptr, buf1);
    gemm_h<0><<<dim3(nb128), blk, 0, stream>>>(buf1, wt_e2, b_e2, nullptr, nullptr, buf0);
    // actor
    gemm_h<0><<<dim3(nb128), blk, 0, stream>>>(buf0, wt_a0, b_a0, nullptr, nullptr, buf1);
    gemm_h<1><<<dim3(nb128), blk, 0, stream>>>(buf1, wt_a1, b_a1, nullptr, nullptr, probs);
    // critic
    gemm_h<0><<<dim3(nb128), blk, 0, stream>>>(buf0, wt_c0, b_c0, nullptr, nullptr, buf1);
    gemm_h<2><<<dim3(nb128), blk, 0, stream>>>(buf1, wt_c1, b_c1, W_c2, b_c2, crit);
}

// Round 4
// 741.678 us; speedup vs baseline: 1.4819x; 1.0548x over previous
//
#include <hip/hip_runtime.h>
#include <hip/hip_bf16.h>

#define F_IN   1024
#define H_DIM  128
#define D_VQE  64
#define K_CODES 512

typedef __attribute__((ext_vector_type(8))) short s8v;   // 8 bf16 = one MFMA A/B frag
typedef __attribute__((ext_vector_type(4))) float f4v;   // MFMA C/D frag

static __device__ __forceinline__ unsigned f2bf(float f) {
    unsigned u = __builtin_bit_cast(unsigned, f);
    return (u + 0x7fffu + ((u >> 16) & 1u)) >> 16;   // RNE, no NaN inputs here
}

static __device__ __forceinline__ f4v mfma16x16x32(s8v a, s8v b, f4v c) {
    return __builtin_amdgcn_mfma_f32_16x16x32_bf16(a, b, c, 0, 0, 0);
}

// ---------------- weight prep: 7 tower weights fp32 [K,N] -> bf16 W^T [N][K] ----------------
__global__ __launch_bounds__(256) void conv_weights(
    const float* __restrict__ W0,  // [1024,128]
    const float* __restrict__ W1, const float* __restrict__ W2,
    const float* __restrict__ W3, const float* __restrict__ W4,
    const float* __restrict__ W5, const float* __restrict__ W6,  // each [128,128]
    short* __restrict__ out)
{
    int g = blockIdx.x * 256 + threadIdx.x;
    if (g < 131072) {
        int n = g >> 10, k = g & 1023;
        out[g] = (short)f2bf(W0[k * 128 + n]);
    } else {
        int r = g - 131072;
        int which = r >> 14, o = r & 16383;
        int n = o >> 7, k = o & 127;
        const float* Ws[6] = {W1, W2, W3, W4, W5, W6};
        out[131072 + which * 16384 + n * 128 + k] = (short)f2bf(Ws[which][k * 128 + n]);
    }
}

// ---------------- e0: [B,1024] fp32 -> relu(x@W_e0+b) -> bf16 [B,128], MFMA ----------------
__global__ __launch_bounds__(256) void gemm_e0(
    const float* __restrict__ A,     // [B,1024] fp32
    const short* __restrict__ Wt,    // [128][1024] bf16 (n-major)
    const float* __restrict__ bias,  // [128] fp32
    short* __restrict__ out)         // [B,128] bf16
{
    __shared__ __align__(16) char smem[36864];
    short* As = (short*)smem;            // [128][72] bf16 chunk (k width 64)
    short* Bs = (short*)(smem + 18432);  // [128][72] bf16 chunk
    short* Cs = (short*)smem;            // [128][136] epilogue staging (overlaps)

    const int t = threadIdx.x;
    const int lane = t & 63, w = t >> 6;
    const int l15 = lane & 15, q = lane >> 4;
    const size_t row0 = (size_t)blockIdx.x * 128;

    f4v acc[2][8];
#pragma unroll
    for (int i = 0; i < 2; ++i)
#pragma unroll
        for (int j = 0; j < 8; ++j) acc[i][j] = {0.f, 0.f, 0.f, 0.f};

    for (int ch = 0; ch < 16; ++ch) {   // k0 = ch*64
        __syncthreads();
#pragma unroll
        for (int i = 0; i < 8; ++i) {
            int c = t + 256 * i;
            int r = c >> 4, c4 = c & 15;
            float4 a4 = *(const float4*)(A + (row0 + r) * 1024 + ch * 64 + c4 * 4);
            unsigned p01 = f2bf(a4.x) | (f2bf(a4.y) << 16);
            unsigned p23 = f2bf(a4.z) | (f2bf(a4.w) << 16);
            *(int2*)(As + r * 72 + c4 * 4) = make_int2((int)p01, (int)p23);
        }
#pragma unroll
        for (int i = 0; i < 4; ++i) {
            int c = t + 256 * i;
            int n = c >> 3, c16 = c & 7;
            *(int4*)(Bs + n * 72 + c16 * 8) = *(const int4*)(Wt + (size_t)n * 1024 + ch * 64 + c16 * 8);
        }
        __syncthreads();
#pragma unroll
        for (int kc = 0; kc < 2; ++kc) {
            int kb = kc * 32 + q * 8;
            s8v a0 = *(const s8v*)(As + (w * 32 + l15) * 72 + kb);
            s8v a1 = *(const s8v*)(As + (w * 32 + 16 + l15) * 72 + kb);
#pragma unroll
            for (int ct = 0; ct < 8; ++ct) {
                s8v b = *(const s8v*)(Bs + (ct * 16 + l15) * 72 + kb);
                acc[0][ct] = mfma16x16x32(a0, b, acc[0][ct]);
                acc[1][ct] = mfma16x16x32(a1, b, acc[1][ct]);
            }
        }
    }

    float bias_v[8];
#pragma unroll
    for (int ct = 0; ct < 8; ++ct) bias_v[ct] = bias[ct * 16 + l15];

    __syncthreads();
#pragma unroll
    for (int rt = 0; rt < 2; ++rt)
#pragma unroll
        for (int ct = 0; ct < 8; ++ct)
#pragma unroll
            for (int reg = 0; reg < 4; ++reg) {
                float v = acc[rt][ct][reg] + bias_v[ct];
                v = fmaxf(v, 0.f);
                Cs[(w * 32 + rt * 16 + q * 4 + reg) * 136 + ct * 16 + l15] = (short)f2bf(v);
            }
    __syncthreads();
#pragma unroll
    for (int i = 0; i < 8; ++i) {
        int c = t + 256 * i;
        int r = c >> 4, c16 = c & 15;
        *(int4*)(out + (row0 + r) * 128 + c16 * 8) = *(const int4*)(Cs + r * 136 + c16 * 8);
    }
}

// ---------------- tower GEMM: bf16 [B,128] @ W[128,128], MFMA, fused epilogues ----------------
// MODE 0: relu -> bf16 [B,128];  1: softmax -> fp32 [B,128];  2: relu+dot(w2)+b2 -> fp32 [B]
template<int MODE>
__global__ __launch_bounds__(256) void gemm_h(
    const short* __restrict__ A,     // [B,128] bf16
    const short* __restrict__ Wt,    // [128][128] bf16 (n-major)
    const float* __restrict__ bias,  // [128] fp32
    const float* __restrict__ w2,    // [128] fp32 (MODE 2)
    const float* __restrict__ b2,    // [1]   fp32 (MODE 2)
    void* __restrict__ outv)
{
    __shared__ __align__(16) char smem[53248];
    short* As = (short*)smem;            // [128][72] bf16 chunk (k width 64)
    short* Bs = (short*)(smem + 18432);  // [128][136] bf16 full weights
    short* Cs = (short*)smem;            // [128][136] epilogue staging (MODE 0)

    const int t = threadIdx.x;
    const int lane = t & 63, w = t >> 6;
    const int l15 = lane & 15, q = lane >> 4;
    const size_t row0 = (size_t)blockIdx.x * 128;

#pragma unroll
    for (int i = 0; i < 8; ++i) {
        int c = t + 256 * i;
        int n = c >> 4, c16 = c & 15;
        *(int4*)(Bs + n * 136 + c16 * 8) = *(const int4*)(Wt + n * 128 + c16 * 8);
    }

    f4v acc[2][8];
#pragma unroll
    for (int i = 0; i < 2; ++i)
#pragma unroll
        for (int j = 0; j < 8; ++j) acc[i][j] = {0.f, 0.f, 0.f, 0.f};

#pragma unroll
    for (int half = 0; half < 2; ++half) {
        __syncthreads();   // first iter: also covers Bs staging
#pragma unroll
        for (int i = 0; i < 4; ++i) {
            int c = t + 256 * i;
            int r = c >> 3, c16 = c & 7;
            *(int4*)(As + r * 72 + c16 * 8) = *(const int4*)(A + (row0 + r) * 128 + half * 64 + c16 * 8);
        }
        __syncthreads();
#pragma unroll
        for (int kc = 0; kc < 2; ++kc) {
            int kb = kc * 32 + q * 8;
            int kg = half * 64 + kb;
            s8v a0 = *(const s8v*)(As + (w * 32 + l15) * 72 + kb);
            s8v a1 = *(const s8v*)(As + (w * 32 + 16 + l15) * 72 + kb);
#pragma unroll
            for (int ct = 0; ct < 8; ++ct) {
                s8v b = *(const s8v*)(Bs + (ct * 16 + l15) * 136 + kg);
                acc[0][ct] = mfma16x16x32(a0, b, acc[0][ct]);
                acc[1][ct] = mfma16x16x32(a1, b, acc[1][ct]);
            }
        }
    }

    float bias_v[8];
#pragma unroll
    for (int ct = 0; ct < 8; ++ct) bias_v[ct] = bias[ct * 16 + l15];

    if (MODE == 0) {
        short* out = (short*)outv;
        __syncthreads();
#pragma unroll
        for (int rt = 0; rt < 2; ++rt)
#pragma unroll
            for (int ct = 0; ct < 8; ++ct)
#pragma unroll
                for (int reg = 0; reg < 4; ++reg) {
                    float v = acc[rt][ct][reg] + bias_v[ct];
                    v = fmaxf(v, 0.f);
                    Cs[(w * 32 + rt * 16 + q * 4 + reg) * 136 + ct * 16 + l15] = (short)f2bf(v);
                }
        __syncthreads();
#pragma unroll
        for (int i = 0; i < 8; ++i) {
            int c = t + 256 * i;
            int r = c >> 4, c16 = c & 15;
            *(int4*)(out + (row0 + r) * 128 + c16 * 8) = *(const int4*)(Cs + r * 136 + c16 * 8);
        }
    } else if (MODE == 1) {
        float* out = (float*)outv;
#pragma unroll
        for (int rt = 0; rt < 2; ++rt)
#pragma unroll
            for (int reg = 0; reg < 4; ++reg) {
                size_t m = row0 + w * 32 + rt * 16 + q * 4 + reg;
                float v[8];
                float mx = -3.4e38f;
#pragma unroll
                for (int ct = 0; ct < 8; ++ct) { v[ct] = acc[rt][ct][reg] + bias_v[ct]; mx = fmaxf(mx, v[ct]); }
#pragma unroll
                for (int off = 1; off < 16; off <<= 1) mx = fmaxf(mx, __shfl_xor(mx, off, 64));
                float s = 0.f;
#pragma unroll
                for (int ct = 0; ct < 8; ++ct) { v[ct] = __expf(v[ct] - mx); s += v[ct]; }
#pragma unroll
                for (int off = 1; off < 16; off <<= 1) s += __shfl_xor(s, off, 64);
                float inv = 1.0f / s;
#pragma unroll
                for (int ct = 0; ct < 8; ++ct) out[m * 128 + ct * 16 + l15] = v[ct] * inv;
            }
    } else {
        float* out = (float*)outv;
        float w2v[8];
#pragma unroll
        for (int ct = 0; ct < 8; ++ct) w2v[ct] = w2[ct * 16 + l15];
        float b2s = b2[0];
#pragma unroll
        for (int rt = 0; rt < 2; ++rt)
#pragma unroll
            for (int reg = 0; reg < 4; ++reg) {
                size_t m = row0 + w * 32 + rt * 16 + q * 4 + reg;
                float p = 0.f;
#pragma unroll
                for (int ct = 0; ct < 8; ++ct) p += fmaxf(acc[rt][ct][reg] + bias_v[ct], 0.f) * w2v[ct];
#pragma unroll
                for (int off = 1; off < 16; off <<= 1) p += __shfl_xor(p, off, 64);
                if (l15 == 0) out[m] = p + b2s;
            }
    }
}

// ---------------- xq projection: fp32, bitwise-identical chains to the verified gemm_n64 ----------------
// 1 row/lane, 16 cols/thread (wave w -> col quarter w). Per-output single fma chain, k ascending.
// W_p values come in via scalar loads (wave-uniform address after readfirstlane).
__global__ __launch_bounds__(256) void proj64(
    const float* __restrict__ A,     // x [B,1024]
    const float* __restrict__ W,     // W_p [1024,64]
    const float* __restrict__ bias,  // [64]
    float* __restrict__ C)           // xq [B,64]
{
    const int t = threadIdx.x;
    const int lane = t & 63;
    const int c0 = __builtin_amdgcn_readfirstlane((t >> 6) << 4);  // wave-uniform col base
    const size_t row = (size_t)blockIdx.x * 64 + lane;
    const float* xr = A + row * 1024;

    float acc[16];
#pragma unroll
    for (int c = 0; c < 16; ++c) acc[c] = 0.f;

    for (int k4 = 0; k4 < 1024; k4 += 4) {
        float4 xv = *(const float4*)(xr + k4);
        float xs[4] = {xv.x, xv.y, xv.z, xv.w};
#pragma unroll
        for (int kk = 0; kk < 4; ++kk) {
            const float* wrow = W + (size_t)(k4 + kk) * 64 + c0;   // uniform -> s_load
#pragma unroll
            for (int c = 0; c < 16; ++c)
                acc[c] = __builtin_fmaf(xs[kk], wrow[c], acc[c]);
        }
    }
#pragma unroll
    for (int c = 0; c < 16; c += 4) {
        float4 o = {acc[c] + bias[c0 + c], acc[c + 1] + bias[c0 + c + 1],
                    acc[c + 2] + bias[c0 + c + 2], acc[c + 3] + bias[c0 + c + 3]};
        *(float4*)(C + row * 64 + c0 + c) = o;
    }
}

// ---------------- VQ part 1: E in VGPRs (2 codes/thread), xq via scalar loads ----------------
// Replicates round-3's verified fp32 arithmetic bit-for-bit:
//   dot: 4 chains by d%4, combined (d0+d1)+(d2+d3); en/sx: single ascending fma chains;
//   dist = sx - 2.0f*dot + en; argmin: lexicographic (dist, j) == ascending strict-<.
__global__ __launch_bounds__(256) void vq_part(
    const float* __restrict__ xq, const float* __restrict__ E,
    unsigned long long* __restrict__ part)    // [B][4] per-wave best keys
{
    __shared__ float sxs[64];
    const int t = threadIdx.x;
    const int lane = t & 63, w = t >> 6;
    const size_t row0 = (size_t)blockIdx.x * 64;
    const int j0 = 2 * t, j1 = 2 * t + 1;

    // load this thread's two codebook rows into registers
    float e0r[64], e1r[64];
#pragma unroll
    for (int d = 0; d < 64; d += 4) {
        float4 v = *(const float4*)(E + (size_t)j0 * 64 + d);
        e0r[d] = v.x; e0r[d + 1] = v.y; e0r[d + 2] = v.z; e0r[d + 3] = v.w;
        float4 u = *(const float4*)(E + (size_t)j1 * 64 + d);
        e1r[d] = u.x; e1r[d + 1] = u.y; e1r[d + 2] = u.z; e1r[d + 3] = u.w;
    }
    float en0 = 0.f, en1 = 0.f;
#pragma unroll
    for (int d = 0; d < 64; ++d) {
        en0 = __builtin_fmaf(e0r[d], e0r[d], en0);
        en1 = __builtin_fmaf(e1r[d], e1r[d], en1);
    }

    // sx for the block's 64 rows (wave 0), single ascending chain per row
    if (w == 0) {
        const float* xr = xq + (row0 + lane) * 64;
        float sx = 0.f;
#pragma unroll
        for (int d = 0; d < 64; d += 4) {
            float4 v = *(const float4*)(xr + d);
            sx = __builtin_fmaf(v.x, v.x, sx);
            sx = __builtin_fmaf(v.y, v.y, sx);
            sx = __builtin_fmaf(v.z, v.z, sx);
            sx = __builtin_fmaf(v.w, v.w, sx);
        }
        sxs[lane] = sx;
    }
    __syncthreads();

    for (int rr = 0; rr < 64; rr += 2) {
        const float* x0 = xq + (row0 + rr) * 64;       // uniform -> s_load
        const float* x1 = x0 + 64;
        float a[2][2][4];
#pragma unroll
        for (int r = 0; r < 2; ++r)
#pragma unroll
            for (int cd = 0; cd < 2; ++cd)
#pragma unroll
                for (int c = 0; c < 4; ++c) a[r][cd][c] = 0.f;

#pragma unroll
        for (int d = 0; d < 64; ++d) {
            float xv0 = x0[d];
            float xv1 = x1[d];
            int c = d & 3;
            a[0][0][c] = __builtin_fmaf(xv0, e0r[d], a[0][0][c]);
            a[0][1][c] = __builtin_fmaf(xv0, e1r[d], a[0][1][c]);
            a[1][0][c] = __builtin_fmaf(xv1, e0r[d], a[1][0][c]);
            a[1][1][c] = __builtin_fmaf(xv1, e1r[d], a[1][1][c]);
        }

#pragma unroll
        for (int r = 0; r < 2; ++r) {
            float sx = sxs[rr + r];
            float dot0 = (a[r][0][0] + a[r][0][1]) + (a[r][0][2] + a[r][0][3]);
            float dot1 = (a[r][1][0] + a[r][1][1]) + (a[r][1][2] + a[r][1][3]);
            float dist0 = sx - 2.0f * dot0 + en0;
            float dist1 = sx - 2.0f * dot1 + en1;
            unsigned long long k0 = ((unsigned long long)__float_as_uint(dist0) << 32) | (unsigned)j0;
            unsigned long long k1 = ((unsigned long long)__float_as_uint(dist1) << 32) | (unsigned)j1;
            unsigned long long key = (k1 < k0) ? k1 : k0;
#pragma unroll
            for (int off = 1; off < 64; off <<= 1) {
                unsigned long long o = __shfl_xor(key, off, 64);
                if (o < key) key = o;
            }
            if (lane == 0) part[(row0 + rr + r) * 4 + w] = key;
        }
    }
}

// ---------------- VQ part 2: merge 4 per-wave keys per row; idx + loss accumulation ----------------
__global__ __launch_bounds__(256) void vq_merge(
    const unsigned long long* __restrict__ part,
    float* __restrict__ idxo, float* __restrict__ accum)
{
    __shared__ float wsum[4];
    const int t = threadIdx.x;
    const size_t row = (size_t)blockIdx.x * 256 + t;
    unsigned long long k = part[row * 4];
#pragma unroll
    for (int i = 1; i < 4; ++i) {
        unsigned long long o = part[row * 4 + i];
        if (o < k) k = o;
    }
    idxo[row] = (float)(unsigned)(k & 0xffffffffULL);
    float dist = __uint_as_float((unsigned)(k >> 32));
    for (int off = 32; off > 0; off >>= 1) dist += __shfl_down(dist, off, 64);
    if ((t & 63) == 0) wsum[t >> 6] = dist;
    __syncthreads();
    if (t == 0) atomicAdd(accum, wsum[0] + wsum[1] + wsum[2] + wsum[3]);
}

__global__ void vq_fin(const float* __restrict__ accum, float* __restrict__ out, float scale)
{
    out[0] = accum[0] * scale;
}

extern "C" void kernel_launch(void* const* d_in, const int* in_sizes, int n_in,
                              void* d_out, int out_size, void* d_ws, size_t ws_size,
                              hipStream_t stream)
{
    const float* x    = (const float*)d_in[0];
    const float* W_e0 = (const float*)d_in[1];
    const float* b_e0 = (const float*)d_in[2];
    const float* W_e1 = (const float*)d_in[3];
    const float* b_e1 = (const float*)d_in[4];
    const float* W_e2 = (const float*)d_in[5];
    const float* b_e2 = (const float*)d_in[6];
    const float* W_p  = (const float*)d_in[7];
    const float* b_p  = (const float*)d_in[8];
    const float* E    = (const float*)d_in[9];
    const float* W_a0 = (const float*)d_in[10];
    const float* b_a0 = (const float*)d_in[11];
    const float* W_a1 = (const float*)d_in[12];
    const float* b_a1 = (const float*)d_in[13];
    const float* W_c0 = (const float*)d_in[14];
    const float* b_c0 = (const float*)d_in[15];
    const float* W_c1 = (const float*)d_in[16];
    const float* b_c1 = (const float*)d_in[17];
    const float* W_c2 = (const float*)d_in[18];
    const float* b_c2 = (const float*)d_in[19];

    const size_t B = (size_t)in_sizes[0] / F_IN;   // 65536

    // ws: buf0 bf16 | buf1 bf16 | wt bf16 | xq fp32 | part u64 | accum
    short* buf0 = (short*)d_ws;                       // B*128 bf16
    short* buf1 = buf0 + B * H_DIM;                   // B*128 bf16
    short* wt   = buf1 + B * H_DIM;                   // 229376 bf16
    short* wt_e0 = wt;                                // [128][1024]
    short* wt_e1 = wt + 131072;                       // [128][128] each
    short* wt_e2 = wt_e1 + 16384;
    short* wt_a0 = wt_e2 + 16384;
    short* wt_a1 = wt_a0 + 16384;
    short* wt_c0 = wt_a1 + 16384;
    short* wt_c1 = wt_c0 + 16384;
    float* xq    = (float*)(wt + 229376);             // B*64 fp32
    unsigned long long* part = (unsigned long long*)(xq + B * D_VQE);  // B*4 u64 (8B-aligned)
    float* accum = (float*)(part + B * 4);

    // d_out is fp32: probs [B,128] | critic [B] | vq_loss [1] | idx [B]
    float* out   = (float*)d_out;
    float* probs = out;
    float* crit  = out + B * H_DIM;
    float* loss  = crit + B;
    float* idxo  = loss + 1;

    hipMemsetAsync(accum, 0, sizeof(float), stream);

    dim3 blk(256);
    const int nb128 = (int)(B / 128);

    conv_weights<<<dim3(896), blk, 0, stream>>>(W_e0, W_e1, W_e2, W_a0, W_a1, W_c0, W_c1, wt);

    // VQ path (fp32, chains bitwise-identical to the verified round-3 kernels)
    proj64<<<dim3((int)(B / 64)), blk, 0, stream>>>(x, W_p, b_p, xq);
    vq_part<<<dim3((int)(B / 64)), blk, 0, stream>>>(xq, E, part);
    vq_merge<<<dim3((int)(B / 256)), blk, 0, stream>>>(part, idxo, accum);
    vq_fin<<<1, 1, 0, stream>>>(accum, loss, 1.25f / ((float)B * (float)D_VQE));

    // tower: bf16 MFMA
    gemm_e0<<<dim3(nb128), blk, 0, stream>>>(x, wt_e0, b_e0, buf0);
    gemm_h<0><<<dim3(nb128), blk, 0, stream>>>(buf0, wt_e1, b_e1, nullptr, nullptr, buf1);
    gemm_h<0><<<dim3(nb128), blk, 0, stream>>>(buf1, wt_e2, b_e2, nullptr, nullptr, buf0);
    gemm_h<0><<<dim3(nb128), blk, 0, stream>>>(buf0, wt_a0, b_a0, nullptr, nullptr, buf1);
    gemm_h<1><<<dim3(nb128), blk, 0, stream>>>(buf1, wt_a1, b_a1, nullptr, nullptr, probs);
    gemm_h<0><<<dim3(nb128), blk, 0, stream>>>(buf0, wt_c0, b_c0, nullptr, nullptr, buf1);
    gemm_h<2><<<dim3(nb128), blk, 0, stream>>>(buf1, wt_c1, b_c1, W_c2, b_c2, crit);
}